// Round 2
// baseline (433.891 us; speedup 1.0000x reference)
//
#include <hip/hip_runtime.h>

#define THREADS 256

// Each "chunk" = 12 contiguous floats = exactly 4 complete joints (3 coords each).
// Loads are 3x float4 per input array per chunk: 48B-aligned, fully coalesced in
// aggregate across the wave. Memory-bound kernel; compute is trivial.
__global__ __launch_bounds__(THREADS) void myloss_kernel(
    const float* __restrict__ pred, const float* __restrict__ lab,
    float* __restrict__ out, int n_chunks, float scale)
{
    float acc = 0.0f;
    const int stride = gridDim.x * blockDim.x;
    for (int c = blockIdx.x * blockDim.x + threadIdx.x; c < n_chunks; c += stride) {
        const float4* p4 = reinterpret_cast<const float4*>(pred) + (size_t)3 * c;
        const float4* l4 = reinterpret_cast<const float4*>(lab)  + (size_t)3 * c;
        float4 pa = p4[0], pb = p4[1], pc = p4[2];
        float4 la = l4[0], lb = l4[1], lc = l4[2];
        float pp[12] = {pa.x, pa.y, pa.z, pa.w, pb.x, pb.y, pb.z, pb.w,
                        pc.x, pc.y, pc.z, pc.w};
        float ll[12] = {la.x, la.y, la.z, la.w, lb.x, lb.y, lb.z, lb.w,
                        lc.x, lc.y, lc.z, lc.w};
        #pragma unroll
        for (int j = 0; j < 4; ++j) {
            float d0 = pp[3*j + 0] - ll[3*j + 0];
            float d1 = pp[3*j + 1] - ll[3*j + 1];
            float d2 = pp[3*j + 2] - ll[3*j + 2];
            float s2 = d2 * d2;
            float full = (d0*d0 + d1*d1 + s2) * (1.0f / 3.0f);
            // mask uses the PREDICTION's confidence coord (p[...,2] > 0.5)
            acc += (pp[3*j + 2] > 0.5f) ? full : s2;
        }
    }

    // 64-lane wave reduction
    #pragma unroll
    for (int off = 32; off > 0; off >>= 1)
        acc += __shfl_down(acc, off, 64);

    __shared__ float wave_sums[THREADS / 64];
    const int lane = threadIdx.x & 63;
    const int wid  = threadIdx.x >> 6;
    if (lane == 0) wave_sums[wid] = acc;
    __syncthreads();

    if (threadIdx.x == 0) {
        float s = 0.0f;
        #pragma unroll
        for (int w = 0; w < THREADS / 64; ++w) s += wave_sums[w];
        atomicAdd(out, s * scale);  // device-scope by default on CDNA
    }
}

extern "C" void kernel_launch(void* const* d_in, const int* in_sizes, int n_in,
                              void* d_out, int out_size, void* d_ws, size_t ws_size,
                              hipStream_t stream) {
    const float* pred = (const float*)d_in[0];
    const float* lab  = (const float*)d_in[1];
    float* out = (float*)d_out;

    const long long total = in_sizes[0];          // B * 54
    const long long B = total / 54;
    const int n_chunks = (int)(total / 12);       // 12 floats per chunk (4 joints)

    // d_out is re-poisoned to 0xAA before every timed launch — zero it.
    hipMemsetAsync(out, 0, sizeof(float), stream);

    const int blocks = 2048;                      // grid-stride, ~8 blocks/CU
    myloss_kernel<<<blocks, THREADS, 0, stream>>>(pred, lab, out, n_chunks,
                                                  1.0f / (float)B);
}